// Round 1
// baseline (263.322 us; speedup 1.0000x reference)
//
#include <hip/hip_runtime.h>
#include <hip/hip_bf16.h>

#define B_  4
#define C_  256
#define C2_ 128
#define N_  4096
#define LOG2E 1.4426950408889634f

typedef unsigned short u16;
typedef __attribute__((ext_vector_type(8))) short bf16x8;  // 8 bf16 in 4 VGPRs
typedef __attribute__((ext_vector_type(4))) short s16x4;   // 4 bf16 in 2 VGPRs
typedef __attribute__((ext_vector_type(4))) float f32x4;

static __device__ __forceinline__ u16 f2bf(float f) {
    return __builtin_bit_cast(u16, __float2bfloat16(f));
}
static __device__ __forceinline__ float bf2f(u16 u) {
    return __bfloat162float(__builtin_bit_cast(__hip_bfloat16, u));
}
static __device__ __forceinline__ bf16x8 cvt8(const float* p) {
    u16 t[8];
#pragma unroll
    for (int j = 0; j < 8; ++j) t[j] = f2bf(p[j]);
    return *(const bf16x8*)t;
}
// LDS b64-pair load/store: rows are 8B-aligned but NOT 16B-aligned (conflict-
// aware leading dims), so b128 is illegal; two ds_read_b64 per fragment.
static __device__ __forceinline__ bf16x8 lds8(const u16* p) {
    s16x4 lo = *(const s16x4*)p;
    s16x4 hi = *(const s16x4*)(p + 4);
    return __builtin_shufflevector(lo, hi, 0, 1, 2, 3, 4, 5, 6, 7);
}
static __device__ __forceinline__ void st8(u16* p, bf16x8 v) {
    *(s16x4*)p       = __builtin_shufflevector(v, v, 0, 1, 2, 3);
    *(s16x4*)(p + 4) = __builtin_shufflevector(v, v, 4, 5, 6, 7);
}

// ---------------------------------------------------------------------------
// Kernel 1 (projx): fused x-transpose + 3-way MFMA projection.
// R0 change: grid 256 -> 512 by splitting each block into two c2-halves.
// Old grid was 1 block/CU = 1 wave/SIMD (zero latency hiding). Blocks i and
// i+256 share the same x tile and land on the same XCD (L2 reuse).
// LDS leading dim 264 -> 268 (536B rows, ~2-way banks instead of 8-way) with
// b64-pair fragment reads.
// ---------------------------------------------------------------------------
#define XW 268

__global__ __launch_bounds__(256, 2) void projx_kernel(
    const float* __restrict__ x,
    const float* __restrict__ wt, const float* __restrict__ wp,
    const float* __restrict__ wg,
    const float* __restrict__ b_theta, const float* __restrict__ b_phi,
    const float* __restrict__ b_g,
    u16* __restrict__ Q, u16* __restrict__ K, u16* __restrict__ V) {
    __shared__ __align__(16) u16 XTs[64][XW];   // 34304 B
    __shared__ __align__(16) u16 Ws[64][XW];    // 34304 B -> 2 blocks/CU
    u16 (*Vt)[72] = (u16(*)[72])XTs;            // [64][72] overlay after af load

    int bid = blockIdx.x;
    int h   = bid >> 8;            // c2-half (0/1); pair (i, i+256) shares x tile
    int r2  = bid & 255;
    int b   = r2 >> 6;
    int n0  = (r2 & 63) * 64;
    int tid = threadIdx.x;
    int wave = tid >> 6, lane = tid & 63, quad = (lane >> 4) & 3, l16 = lane & 15;

    // ---- stage + transpose x tile [256 c][64 n] fp32 -> XTs[n][c] bf16 ----
#pragma unroll
    for (int it = 0; it < 8; ++it) {
        int idx = it * 256 + tid;
        int q = idx & 15, p = idx >> 4;
        const float* r0 = x + ((size_t)b * C_ + 2 * p) * N_ + n0 + 4 * q;
        float4 v0 = *(const float4*)r0;
        float4 v1 = *(const float4*)(r0 + N_);
        const float* f0 = (const float*)&v0;
        const float* f1 = (const float*)&v1;
#pragma unroll
        for (int j = 0; j < 4; ++j) {
            unsigned pk = (unsigned)f2bf(f0[j]) | ((unsigned)f2bf(f1[j]) << 16);
            *(unsigned*)&XTs[4 * q + j][2 * p] = pk;
        }
    }
    __syncthreads();

    // A fragments: wave's 16 n-rows, resident whole kernel
    bf16x8 af[8];
#pragma unroll
    for (int ks = 0; ks < 8; ++ks)
        af[ks] = lds8(&XTs[wave * 16 + l16][ks * 32 + quad * 8]);
    __syncthreads();   // XTs consumed -> Vt may overlay

    const float* wms[3]    = { wt, wp, wg };
    const float* biases[3] = { b_theta, b_phi, b_g };

#pragma unroll
    for (int mat = 0; mat < 3; ++mat) {
        const float* wm = wms[mat];
        const float* bias = biases[mat];
        // ---- stage this block's weight half [64 c2][256 c] fp32 -> bf16 ----
#pragma unroll
        for (int it = 0; it < 8; ++it) {
            int idx = it * 256 + tid;
            int row = idx >> 5, c8 = (idx & 31) * 8;
            const float* src = wm + (size_t)(h * 64 + row) * C_ + c8;
            float w8[8];
            *(float4*)&w8[0] = *(const float4*)src;
            *(float4*)&w8[4] = *(const float4*)(src + 4);
            st8(&Ws[row][c8], cvt8(w8));
        }
        __syncthreads();

        f32x4 acc[4];
#pragma unroll
        for (int i = 0; i < 4; ++i) acc[i] = (f32x4){0.f, 0.f, 0.f, 0.f};
#pragma unroll
        for (int ct = 0; ct < 4; ++ct)
#pragma unroll
            for (int ks = 0; ks < 8; ++ks) {
                bf16x8 bf = lds8(&Ws[ct * 16 + l16][ks * 32 + quad * 8]);
                acc[ct] = __builtin_amdgcn_mfma_f32_16x16x32_bf16(
                    af[ks], bf, acc[ct], 0, 0, 0);
            }

        if (mat < 2) {
            u16* dst = mat == 0 ? Q : K;
            float scl = mat == 0 ? LOG2E : 1.0f;
#pragma unroll
            for (int ct = 0; ct < 4; ++ct) {
                int c2 = h * 64 + ct * 16 + l16;
                float bb = bias[c2];
#pragma unroll
                for (int r = 0; r < 4; ++r) {
                    int n = n0 + wave * 16 + quad * 4 + r;
                    dst[((size_t)b * N_ + n) * C2_ + c2] =
                        f2bf((acc[ct][r] + bb) * scl);
                }
            }
        } else {
#pragma unroll
            for (int ct = 0; ct < 4; ++ct) {
                int c2 = h * 64 + ct * 16 + l16;
                float bb = bias[c2];
#pragma unroll
                for (int r = 0; r < 4; ++r)
                    Vt[ct * 16 + l16][wave * 16 + quad * 4 + r] =
                        f2bf(acc[ct][r] + bb);
            }
        }
        __syncthreads();   // Ws free for restaging / Vt complete
    }

    // cooperative V[b][h*64 + 0..63][n0..n0+63] write: 64 rows x 8 uint4
#pragma unroll
    for (int it = 0; it < 2; ++it) {
        int idx = it * 256 + tid;
        int row = idx >> 3, n8 = (idx & 7) * 8;
        *(uint4*)(V + ((size_t)b * C2_ + h * 64 + row) * N_ + n0 + n8) =
            *(const uint4*)&Vt[row][n8];
    }
}

// ---------------------------------------------------------------------------
// Kernel 2: flash attention, BM=128, BN=64.
// R0 changes:
//  - P scratch aliased INTO the Ks buffer (P only live after all QK reads;
//    enforced by one extra barrier per tile). LDS 54272 -> 37376 B -> 4
//    blocks/CU, launched at S=8 (grid 1024) to fill it (was 2 blk/CU @ 17%
//    occupancy).
//  - Conflict-aware leading dims: Ks 140 (280B rows, ~2-way), Vs 76 (152B,
//    ~2-way), Ps 68 (136B, 4-way). All fragment reads via ds_read_b64 pairs
//    (old D+8 / BN+8 pads were 8-way conflicted b128s -> 4.7M SQ_LDS_BANK_
//    CONFLICT per dispatch).
//  - exp2 runs on registers BEFORE the new barrier; P packed to 16 dwords to
//    bound live-across-barrier VGPRs.
// ---------------------------------------------------------------------------
#define KS_LD 140
#define VS_LD 76
#define PS_LD 68

__global__ __launch_bounds__(256, 4) void attn_kernel(
    const u16* __restrict__ Q, const u16* __restrict__ K,
    const u16* __restrict__ V, u16* __restrict__ AO,
    u16* __restrict__ Opb, float* __restrict__ lsum, int nsplit) {
    const int BM = 128, BN = 64, D = C2_;
    const int per = B_ * (N_ / BM);      // 128
    int s    = blockIdx.x / per;
    int r0   = blockIdx.x % per;
    int b    = r0 / (N_ / BM);
    int m0   = (r0 % (N_ / BM)) * BM;
    int tid  = threadIdx.x;
    int wave = tid >> 6, lane = tid & 63, quad = (lane >> 4) & 3, l16 = lane & 15;

    __shared__ __align__(16) u16 Ks[BN][KS_LD];    // 17920 B
    __shared__ __align__(16) u16 Vs[C2_][VS_LD];   // 19456 B ; total 37376
    // per-wave P scratch [32][PS_LD] aliased into Ks: 4*32*68 = 8704 u16 <= 8960
    u16* Ps = &Ks[0][0] + wave * (32 * PS_LD);

    bf16x8 qf[2][4];
#pragma unroll
    for (int ms = 0; ms < 2; ++ms) {
        const u16* qp = Q + ((size_t)b * N_ + m0 + wave * 32 + ms * 16 + l16) * D;
#pragma unroll
        for (int kk = 0; kk < 4; ++kk)
            qf[ms][kk] = *(const bf16x8*)(qp + kk * 32 + quad * 8);
    }

    float l_r[2][4] = {{0.f, 0.f, 0.f, 0.f}, {0.f, 0.f, 0.f, 0.f}};
    f32x4 o_acc[2][8];
#pragma unroll
    for (int ms = 0; ms < 2; ++ms)
#pragma unroll
        for (int i = 0; i < 8; ++i) o_acc[ms][i] = (f32x4){0.f, 0.f, 0.f, 0.f};

    const int tiles = N_ / BN;                 // 64
    const int base = tiles / nsplit, rem = tiles % nsplit;
    const int t0 = s * base + (s < rem ? s : rem);
    const int cnt = base + (s < rem ? 1 : 0);
    const int nt0 = t0 * BN, nt1 = (t0 + cnt) * BN;

    for (int nt = nt0; nt < nt1; nt += BN) {
        const u16* kp = K + ((size_t)b * N_ + nt) * D;
#pragma unroll
        for (int it = 0; it < 4; ++it) {
            int idx = it * 256 + tid;
            int row = idx >> 4, col = (idx & 15) * 8;
            uint4 raw = *(const uint4*)(kp + row * D + col);
            *(uint2*)&Ks[row][col]     = make_uint2(raw.x, raw.y);
            *(uint2*)&Ks[row][col + 4] = make_uint2(raw.z, raw.w);
        }
#pragma unroll
        for (int it = 0; it < 4; ++it) {
            int idx = it * 256 + tid;
            int row = idx >> 3, col = (idx & 7) * 8;
            uint4 raw = *(const uint4*)(V + ((size_t)b * C2_ + row) * N_ + nt + col);
            *(uint2*)&Vs[row][col]     = make_uint2(raw.x, raw.y);
            *(uint2*)&Vs[row][col + 4] = make_uint2(raw.z, raw.w);
        }
        __syncthreads();

        f32x4 sc[2][4];
#pragma unroll
        for (int nn = 0; nn < 4; ++nn) {
            f32x4 a0 = (f32x4){0.f, 0.f, 0.f, 0.f};
            f32x4 a1 = (f32x4){0.f, 0.f, 0.f, 0.f};
#pragma unroll
            for (int kk = 0; kk < 4; ++kk) {
                bf16x8 kf = lds8(&Ks[nn * 16 + l16][kk * 32 + quad * 8]);
                a0 = __builtin_amdgcn_mfma_f32_16x16x32_bf16(qf[0][kk], kf, a0, 0, 0, 0);
                a1 = __builtin_amdgcn_mfma_f32_16x16x32_bf16(qf[1][kk], kf, a1, 0, 0, 0);
            }
            sc[0][nn] = a0;
            sc[1][nn] = a1;
        }

        // exp2 + bf16 pack in registers (overlaps other waves' QK phase)
        unsigned pkd[2][4][2];
#pragma unroll
        for (int ms = 0; ms < 2; ++ms)
#pragma unroll
            for (int nn = 0; nn < 4; ++nn)
#pragma unroll
                for (int rp = 0; rp < 2; ++rp) {
                    float p0 = __builtin_amdgcn_exp2f(sc[ms][nn][2 * rp]);
                    float p1 = __builtin_amdgcn_exp2f(sc[ms][nn][2 * rp + 1]);
                    l_r[ms][2 * rp]     += p0;
                    l_r[ms][2 * rp + 1] += p1;
                    pkd[ms][nn][rp] =
                        (unsigned)f2bf(p0) | ((unsigned)f2bf(p1) << 16);
                }

        __syncthreads();   // all waves done reading Ks -> safe to overwrite w/ P

#pragma unroll
        for (int ms = 0; ms < 2; ++ms)
#pragma unroll
            for (int nn = 0; nn < 4; ++nn)
#pragma unroll
                for (int rp = 0; rp < 2; ++rp) {
                    unsigned v = pkd[ms][nn][rp];
                    int rb = (ms * 16 + quad * 4 + 2 * rp) * PS_LD + nn * 16 + l16;
                    Ps[rb]         = (u16)v;
                    Ps[rb + PS_LD] = (u16)(v >> 16);
                }

#pragma unroll
        for (int ks = 0; ks < 2; ++ks) {
            bf16x8 pf0 = lds8(Ps + l16 * PS_LD + ks * 32 + quad * 8);
            bf16x8 pf1 = lds8(Ps + (16 + l16) * PS_LD + ks * 32 + quad * 8);
#pragma unroll
            for (int cs = 0; cs < 8; ++cs) {
                bf16x8 vf = lds8(&Vs[cs * 16 + l16][ks * 32 + quad * 8]);
                o_acc[0][cs] = __builtin_amdgcn_mfma_f32_16x16x32_bf16(pf0, vf, o_acc[0][cs], 0, 0, 0);
                o_acc[1][cs] = __builtin_amdgcn_mfma_f32_16x16x32_bf16(pf1, vf, o_acc[1][cs], 0, 0, 0);
            }
        }
        __syncthreads();   // all P/V reads done before next-tile restage
    }

#pragma unroll
    for (int ms = 0; ms < 2; ++ms)
#pragma unroll
        for (int r = 0; r < 4; ++r) {
            l_r[ms][r] += __shfl_xor(l_r[ms][r], 1);
            l_r[ms][r] += __shfl_xor(l_r[ms][r], 2);
            l_r[ms][r] += __shfl_xor(l_r[ms][r], 4);
            l_r[ms][r] += __shfl_xor(l_r[ms][r], 8);
        }

    if (Opb) {
#pragma unroll
        for (int ms = 0; ms < 2; ++ms) {
#pragma unroll
            for (int cs = 0; cs < 8; ++cs)
#pragma unroll
                for (int r = 0; r < 4; ++r) {
                    size_t row = (size_t)s * (B_ * N_) + (size_t)b * N_ +
                                 m0 + wave * 32 + ms * 16 + quad * 4 + r;
                    Opb[row * C2_ + cs * 16 + l16] = f2bf(o_acc[ms][cs][r]);
                }
            if (l16 == 0)
#pragma unroll
                for (int r = 0; r < 4; ++r) {
                    size_t row = (size_t)s * (B_ * N_) + (size_t)b * N_ +
                                 m0 + wave * 32 + ms * 16 + quad * 4 + r;
                    lsum[row] = l_r[ms][r];
                }
        }
    } else {
#pragma unroll
        for (int ms = 0; ms < 2; ++ms)
#pragma unroll
            for (int cs = 0; cs < 8; ++cs)
#pragma unroll
                for (int r = 0; r < 4; ++r) {
                    float v = o_acc[ms][cs][r] / l_r[ms][r];
                    AO[((size_t)b * N_ + m0 + wave * 32 + ms * 16 + quad * 4 + r) * C2_ +
                       cs * 16 + l16] = f2bf(v);
                }
    }
}

// ---------------------------------------------------------------------------
// Kernel 3: outproj with fused split-K combine.
// R0: __launch_bounds__(256,4); generic over nsplit (now 8); LDS leading dim
// 136 -> 140 (280B rows) with b64-pair fragment reads (was 8-way conflicted).
// LDS: 2*17920 + 256 = 36096 B -> 4 blocks/CU.
// ---------------------------------------------------------------------------
#define OW 140

__global__ __launch_bounds__(256, 4) void outproj_kernel(
    const float* __restrict__ x, const u16* __restrict__ Opb,
    const float* __restrict__ lsum, const u16* __restrict__ AO,
    const float* __restrict__ w_out, const float* __restrict__ b_out,
    float* __restrict__ y, int nsplit) {
    __shared__ __align__(16) u16 As[64][OW];     // 17920 B
    __shared__ __align__(16) u16 Ws2[64][OW];    // 17920 B
    __shared__ float Ls[64];
    int bid = blockIdx.x;
    int per_b = (C_ / 64) * (N_ / 64);   // 256
    int b   = bid / per_b;
    int rem = bid % per_b;
    int c0  = (rem / (N_ / 64)) * 64;
    int n0  = (rem % (N_ / 64)) * 64;
    int tid = threadIdx.x;
    int wave = tid >> 6, lane = tid & 63, quad = (lane >> 4) & 3, l16 = lane & 15;

    // ---- stage w_out tile [64 c][128 c2] fp32 -> Ws2 bf16 (coalesced) ----
#pragma unroll
    for (int it = 0; it < 4; ++it) {
        int idx = it * 256 + tid;
        int row = idx >> 4, c8 = (idx & 15) * 8;
        const float* src = w_out + (size_t)(c0 + row) * C2_ + c8;
        float w8[8];
        *(float4*)&w8[0] = *(const float4*)src;
        *(float4*)&w8[4] = *(const float4*)(src + 4);
        st8(&Ws2[row][c8], cvt8(w8));
    }

    if (nsplit > 1) {   // grid-uniform branch
        if (tid < 64) {
            float L = 0.f;
            for (int s = 0; s < nsplit; ++s)
                L += lsum[(size_t)s * (B_ * N_) + (size_t)b * N_ + n0 + tid];
            Ls[tid] = 1.f / L;
        }
        __syncthreads();
#pragma unroll
        for (int it = 0; it < 4; ++it) {
            int idx = it * 256 + tid;
            int n = idx >> 4, c8 = (idx & 15) * 8;
            float a[8] = {0.f, 0.f, 0.f, 0.f, 0.f, 0.f, 0.f, 0.f};
            for (int s = 0; s < nsplit; ++s) {
                const u16* op = Opb +
                    ((size_t)s * (B_ * N_) + (size_t)b * N_ + n0 + n) * C2_ + c8;
                uint4 raw = *(const uint4*)op;
                const u16* rp = (const u16*)&raw;
#pragma unroll
                for (int j = 0; j < 8; ++j) a[j] += bf2f(rp[j]);
            }
            float inv = Ls[n];
            u16 o[8];
#pragma unroll
            for (int j = 0; j < 8; ++j) o[j] = f2bf(a[j] * inv);
            st8(&As[n][c8], *(const bf16x8*)o);
        }
    } else {
#pragma unroll
        for (int it = 0; it < 4; ++it) {
            int idx = it * 256 + tid;
            int n = idx >> 4, c8 = (idx & 15) * 8;
            uint4 raw = *(const uint4*)(AO + ((size_t)b * N_ + n0 + n) * C2_ + c8);
            *(uint2*)&As[n][c8]     = make_uint2(raw.x, raw.y);
            *(uint2*)&As[n][c8 + 4] = make_uint2(raw.z, raw.w);
        }
    }
    __syncthreads();

    bf16x8 af[4];
#pragma unroll
    for (int kk = 0; kk < 4; ++kk)
        af[kk] = lds8(&Ws2[wave * 16 + l16][kk * 32 + quad * 8]);

    f32x4 acc[4];
#pragma unroll
    for (int i = 0; i < 4; ++i) acc[i] = (f32x4){0.f, 0.f, 0.f, 0.f};

#pragma unroll
    for (int nn = 0; nn < 4; ++nn)
#pragma unroll
        for (int kk = 0; kk < 4; ++kk) {
            bf16x8 bf = lds8(&As[nn * 16 + l16][kk * 32 + quad * 8]);
            acc[nn] = __builtin_amdgcn_mfma_f32_16x16x32_bf16(af[kk], bf, acc[nn], 0, 0, 0);
        }

    int cw = c0 + wave * 16;
    float bo[4];
#pragma unroll
    for (int r = 0; r < 4; ++r) bo[r] = b_out[cw + quad * 4 + r];

#pragma unroll
    for (int nn = 0; nn < 4; ++nn)
#pragma unroll
        for (int r = 0; r < 4; ++r) {
            int c = cw + quad * 4 + r;
            size_t off = ((size_t)b * C_ + c) * N_ + n0 + nn * 16 + l16;
            y[off] = x[off] + bo[r] + acc[nn][r];
        }
}

// ---------------------------------------------------------------------------
extern "C" void kernel_launch(void* const* d_in, const int* in_sizes, int n_in,
                              void* d_out, int out_size, void* d_ws, size_t ws_size,
                              hipStream_t stream) {
    const float* x       = (const float*)d_in[0];
    const float* w_theta = (const float*)d_in[1];
    const float* b_theta = (const float*)d_in[2];
    const float* w_phi   = (const float*)d_in[3];
    const float* b_phi   = (const float*)d_in[4];
    const float* w_g     = (const float*)d_in[5];
    const float* b_g     = (const float*)d_in[6];
    const float* w_out   = (const float*)d_in[7];
    const float* b_out   = (const float*)d_in[8];
    float* y = (float*)d_out;

    const size_t SZ = (size_t)B_ * N_ * C2_;        // 2Mi elements
    u16* Q = (u16*)d_ws;
    u16* K = Q + SZ;
    u16* V = K + SZ;
    char* dyn = (char*)(V + SZ);
    size_t fixedB = 3 * SZ * 2;                      // 12 MiB

    size_t perS = SZ * 2 + (size_t)B_ * N_ * 4;      // Opb bf16 + lsum per split

    int S;
    if      (ws_size >= fixedB + 8 * perS) S = 8;    // grid 1024 = 4 blk/CU
    else if (ws_size >= fixedB + 4 * perS) S = 4;
    else if (ws_size >= fixedB + 2 * perS) S = 2;
    else                                   S = 1;

    u16*   AO  = (u16*)dyn;       // used only when S == 1
    u16*   Opb = nullptr;
    float* ls  = nullptr;
    if (S > 1) {
        Opb = (u16*)dyn;          // aliases AO (AO unused when split)
        ls  = (float*)(Opb + (size_t)S * SZ);
    }

    projx_kernel<<<B_ * (N_ / 64) * 2, 256, 0, stream>>>(
        x, w_theta, w_phi, w_g, b_theta, b_phi, b_g, Q, K, V);
    attn_kernel<<<B_ * (N_ / 128) * S, 256, 0, stream>>>(Q, K, V, AO, Opb, ls, S);
    outproj_kernel<<<B_ * (C_ / 64) * (N_ / 64), 256, 0, stream>>>(
        x, Opb, ls, AO, w_out, b_out, y, S);
}

// Round 2
// 160.300 us; speedup vs baseline: 1.6427x; 1.6427x over previous
//
#include <hip/hip_runtime.h>
#include <hip/hip_bf16.h>

#define B_  4
#define C_  256
#define C2_ 128
#define N_  4096
#define LOG2E 1.4426950408889634f

typedef unsigned short u16;
typedef __attribute__((ext_vector_type(8))) short bf16x8;  // 8 bf16 in 4 VGPRs
typedef __attribute__((ext_vector_type(4))) short s16x4;   // 4 bf16 in 2 VGPRs
typedef __attribute__((ext_vector_type(4))) float f32x4;

static __device__ __forceinline__ u16 f2bf(float f) {
    return __builtin_bit_cast(u16, __float2bfloat16(f));
}
static __device__ __forceinline__ float bf2f(u16 u) {
    return __bfloat162float(__builtin_bit_cast(__hip_bfloat16, u));
}
static __device__ __forceinline__ bf16x8 cvt8(const float* p) {
    u16 t[8];
#pragma unroll
    for (int j = 0; j < 8; ++j) t[j] = f2bf(p[j]);
    return *(const bf16x8*)t;
}
// LDS b64-pair load/store: rows are 8B-aligned but NOT 16B-aligned (conflict-
// aware leading dims), so b128 is illegal; two ds_read_b64 per fragment.
static __device__ __forceinline__ bf16x8 lds8(const u16* p) {
    s16x4 lo = *(const s16x4*)p;
    s16x4 hi = *(const s16x4*)(p + 4);
    return __builtin_shufflevector(lo, hi, 0, 1, 2, 3, 4, 5, 6, 7);
}
static __device__ __forceinline__ void st8(u16* p, bf16x8 v) {
    *(s16x4*)p       = __builtin_shufflevector(v, v, 0, 1, 2, 3);
    *(s16x4*)(p + 4) = __builtin_shufflevector(v, v, 4, 5, 6, 7);
}

// ---------------------------------------------------------------------------
// Kernel 1 (projx): fused x-transpose + 3-way MFMA projection.
// Grid 512: two c2-halves per (b, n-tile); pair (i, i+256) shares the x tile.
// LDS leading dim 268 (536B rows, ~2-way banks) with b64-pair reads.
// ---------------------------------------------------------------------------
#define XW 268

__global__ __launch_bounds__(256, 2) void projx_kernel(
    const float* __restrict__ x,
    const float* __restrict__ wt, const float* __restrict__ wp,
    const float* __restrict__ wg,
    const float* __restrict__ b_theta, const float* __restrict__ b_phi,
    const float* __restrict__ b_g,
    u16* __restrict__ Q, u16* __restrict__ K, u16* __restrict__ V) {
    __shared__ __align__(16) u16 XTs[64][XW];   // 34304 B
    __shared__ __align__(16) u16 Ws[64][XW];    // 34304 B -> 2 blocks/CU
    u16 (*Vt)[72] = (u16(*)[72])XTs;            // [64][72] overlay after af load

    int bid = blockIdx.x;
    int h   = bid >> 8;            // c2-half (0/1)
    int r2  = bid & 255;
    int b   = r2 >> 6;
    int n0  = (r2 & 63) * 64;
    int tid = threadIdx.x;
    int wave = tid >> 6, lane = tid & 63, quad = (lane >> 4) & 3, l16 = lane & 15;

    // ---- stage + transpose x tile [256 c][64 n] fp32 -> XTs[n][c] bf16 ----
#pragma unroll
    for (int it = 0; it < 8; ++it) {
        int idx = it * 256 + tid;
        int q = idx & 15, p = idx >> 4;
        const float* r0 = x + ((size_t)b * C_ + 2 * p) * N_ + n0 + 4 * q;
        float4 v0 = *(const float4*)r0;
        float4 v1 = *(const float4*)(r0 + N_);
        const float* f0 = (const float*)&v0;
        const float* f1 = (const float*)&v1;
#pragma unroll
        for (int j = 0; j < 4; ++j) {
            unsigned pk = (unsigned)f2bf(f0[j]) | ((unsigned)f2bf(f1[j]) << 16);
            *(unsigned*)&XTs[4 * q + j][2 * p] = pk;
        }
    }
    __syncthreads();

    // A fragments: wave's 16 n-rows, resident whole kernel
    bf16x8 af[8];
#pragma unroll
    for (int ks = 0; ks < 8; ++ks)
        af[ks] = lds8(&XTs[wave * 16 + l16][ks * 32 + quad * 8]);
    __syncthreads();   // XTs consumed -> Vt may overlay

    const float* wms[3]    = { wt, wp, wg };
    const float* biases[3] = { b_theta, b_phi, b_g };

#pragma unroll
    for (int mat = 0; mat < 3; ++mat) {
        const float* wm = wms[mat];
        const float* bias = biases[mat];
        // ---- stage this block's weight half [64 c2][256 c] fp32 -> bf16 ----
#pragma unroll
        for (int it = 0; it < 8; ++it) {
            int idx = it * 256 + tid;
            int row = idx >> 5, c8 = (idx & 31) * 8;
            const float* src = wm + (size_t)(h * 64 + row) * C_ + c8;
            float w8[8];
            *(float4*)&w8[0] = *(const float4*)src;
            *(float4*)&w8[4] = *(const float4*)(src + 4);
            st8(&Ws[row][c8], cvt8(w8));
        }
        __syncthreads();

        f32x4 acc[4];
#pragma unroll
        for (int i = 0; i < 4; ++i) acc[i] = (f32x4){0.f, 0.f, 0.f, 0.f};
#pragma unroll
        for (int ct = 0; ct < 4; ++ct)
#pragma unroll
            for (int ks = 0; ks < 8; ++ks) {
                bf16x8 bf = lds8(&Ws[ct * 16 + l16][ks * 32 + quad * 8]);
                acc[ct] = __builtin_amdgcn_mfma_f32_16x16x32_bf16(
                    af[ks], bf, acc[ct], 0, 0, 0);
            }

        if (mat < 2) {
            u16* dst = mat == 0 ? Q : K;
            float scl = mat == 0 ? LOG2E : 1.0f;
#pragma unroll
            for (int ct = 0; ct < 4; ++ct) {
                int c2 = h * 64 + ct * 16 + l16;
                float bb = bias[c2];
#pragma unroll
                for (int r = 0; r < 4; ++r) {
                    int n = n0 + wave * 16 + quad * 4 + r;
                    dst[((size_t)b * N_ + n) * C2_ + c2] =
                        f2bf((acc[ct][r] + bb) * scl);
                }
            }
        } else {
#pragma unroll
            for (int ct = 0; ct < 4; ++ct) {
                int c2 = h * 64 + ct * 16 + l16;
                float bb = bias[c2];
#pragma unroll
                for (int r = 0; r < 4; ++r)
                    Vt[ct * 16 + l16][wave * 16 + quad * 4 + r] =
                        f2bf(acc[ct][r] + bb);
            }
        }
        __syncthreads();   // Ws free for restaging / Vt complete
    }

    // cooperative V[b][h*64 + 0..63][n0..n0+63] write: 64 rows x 8 uint4
#pragma unroll
    for (int it = 0; it < 2; ++it) {
        int idx = it * 256 + tid;
        int row = idx >> 3, n8 = (idx & 7) * 8;
        *(uint4*)(V + ((size_t)b * C2_ + h * 64 + row) * N_ + n0 + n8) =
            *(const uint4*)&Vt[row][n8];
    }
}

// ---------------------------------------------------------------------------
// Kernel 2: flash attention, BM=128, BN=64.
// R1: __launch_bounds__ back to (256,2) — R0's (256,4) forced a 64-VGPR
// budget and spilled the 64-reg o_acc to scratch (FETCH 34->338 MB,
// WRITE 16->366 MB, 3x slower). At natural ~112-128 VGPR the LDS size
// (37376 B, P aliased into Ks) is what sets occupancy: 4 blocks/CU.
// exp2+pack fused into the QK nn-loop so sc[2][4] is never all-live;
// only pkd (16 VGPRs) persists across the alias barrier.
// ---------------------------------------------------------------------------
#define KS_LD 140
#define VS_LD 76
#define PS_LD 68

__global__ __launch_bounds__(256, 2) void attn_kernel(
    const u16* __restrict__ Q, const u16* __restrict__ K,
    const u16* __restrict__ V, u16* __restrict__ AO,
    u16* __restrict__ Opb, float* __restrict__ lsum, int nsplit) {
    const int BM = 128, BN = 64, D = C2_;
    const int per = B_ * (N_ / BM);      // 128
    int s    = blockIdx.x / per;
    int r0   = blockIdx.x % per;
    int b    = r0 / (N_ / BM);
    int m0   = (r0 % (N_ / BM)) * BM;
    int tid  = threadIdx.x;
    int wave = tid >> 6, lane = tid & 63, quad = (lane >> 4) & 3, l16 = lane & 15;

    __shared__ __align__(16) u16 Ks[BN][KS_LD];    // 17920 B
    __shared__ __align__(16) u16 Vs[C2_][VS_LD];   // 19456 B ; total 37376
    // per-wave P scratch [32][PS_LD] aliased into Ks: 4*32*68 = 8704 u16 <= 8960
    u16* Ps = &Ks[0][0] + wave * (32 * PS_LD);

    bf16x8 qf[2][4];
#pragma unroll
    for (int ms = 0; ms < 2; ++ms) {
        const u16* qp = Q + ((size_t)b * N_ + m0 + wave * 32 + ms * 16 + l16) * D;
#pragma unroll
        for (int kk = 0; kk < 4; ++kk)
            qf[ms][kk] = *(const bf16x8*)(qp + kk * 32 + quad * 8);
    }

    float l_r[2][4] = {{0.f, 0.f, 0.f, 0.f}, {0.f, 0.f, 0.f, 0.f}};
    f32x4 o_acc[2][8];
#pragma unroll
    for (int ms = 0; ms < 2; ++ms)
#pragma unroll
        for (int i = 0; i < 8; ++i) o_acc[ms][i] = (f32x4){0.f, 0.f, 0.f, 0.f};

    const int tiles = N_ / BN;                 // 64
    const int base = tiles / nsplit, rem = tiles % nsplit;
    const int t0 = s * base + (s < rem ? s : rem);
    const int cnt = base + (s < rem ? 1 : 0);
    const int nt0 = t0 * BN, nt1 = (t0 + cnt) * BN;

    for (int nt = nt0; nt < nt1; nt += BN) {
        const u16* kp = K + ((size_t)b * N_ + nt) * D;
#pragma unroll
        for (int it = 0; it < 4; ++it) {
            int idx = it * 256 + tid;
            int row = idx >> 4, col = (idx & 15) * 8;
            uint4 raw = *(const uint4*)(kp + row * D + col);
            *(uint2*)&Ks[row][col]     = make_uint2(raw.x, raw.y);
            *(uint2*)&Ks[row][col + 4] = make_uint2(raw.z, raw.w);
        }
#pragma unroll
        for (int it = 0; it < 4; ++it) {
            int idx = it * 256 + tid;
            int row = idx >> 3, col = (idx & 7) * 8;
            uint4 raw = *(const uint4*)(V + ((size_t)b * C2_ + row) * N_ + nt + col);
            *(uint2*)&Vs[row][col]     = make_uint2(raw.x, raw.y);
            *(uint2*)&Vs[row][col + 4] = make_uint2(raw.z, raw.w);
        }
        __syncthreads();

        // QK^T with exp2+pack fused per nn (keeps sc liveness at 8 floats)
        unsigned pkd[2][4][2];
#pragma unroll
        for (int nn = 0; nn < 4; ++nn) {
            f32x4 a0 = (f32x4){0.f, 0.f, 0.f, 0.f};
            f32x4 a1 = (f32x4){0.f, 0.f, 0.f, 0.f};
#pragma unroll
            for (int kk = 0; kk < 4; ++kk) {
                bf16x8 kf = lds8(&Ks[nn * 16 + l16][kk * 32 + quad * 8]);
                a0 = __builtin_amdgcn_mfma_f32_16x16x32_bf16(qf[0][kk], kf, a0, 0, 0, 0);
                a1 = __builtin_amdgcn_mfma_f32_16x16x32_bf16(qf[1][kk], kf, a1, 0, 0, 0);
            }
#pragma unroll
            for (int rp = 0; rp < 2; ++rp) {
                float p0 = __builtin_amdgcn_exp2f(a0[2 * rp]);
                float p1 = __builtin_amdgcn_exp2f(a0[2 * rp + 1]);
                l_r[0][2 * rp]     += p0;
                l_r[0][2 * rp + 1] += p1;
                pkd[0][nn][rp] = (unsigned)f2bf(p0) | ((unsigned)f2bf(p1) << 16);
                float p2 = __builtin_amdgcn_exp2f(a1[2 * rp]);
                float p3 = __builtin_amdgcn_exp2f(a1[2 * rp + 1]);
                l_r[1][2 * rp]     += p2;
                l_r[1][2 * rp + 1] += p3;
                pkd[1][nn][rp] = (unsigned)f2bf(p2) | ((unsigned)f2bf(p3) << 16);
            }
        }

        __syncthreads();   // all waves done reading Ks -> safe to overwrite w/ P

#pragma unroll
        for (int ms = 0; ms < 2; ++ms)
#pragma unroll
            for (int nn = 0; nn < 4; ++nn)
#pragma unroll
                for (int rp = 0; rp < 2; ++rp) {
                    unsigned v = pkd[ms][nn][rp];
                    int rb = (ms * 16 + quad * 4 + 2 * rp) * PS_LD + nn * 16 + l16;
                    Ps[rb]         = (u16)v;
                    Ps[rb + PS_LD] = (u16)(v >> 16);
                }

#pragma unroll
        for (int ks = 0; ks < 2; ++ks) {
            bf16x8 pf0 = lds8(Ps + l16 * PS_LD + ks * 32 + quad * 8);
            bf16x8 pf1 = lds8(Ps + (16 + l16) * PS_LD + ks * 32 + quad * 8);
#pragma unroll
            for (int cs = 0; cs < 8; ++cs) {
                bf16x8 vf = lds8(&Vs[cs * 16 + l16][ks * 32 + quad * 8]);
                o_acc[0][cs] = __builtin_amdgcn_mfma_f32_16x16x32_bf16(pf0, vf, o_acc[0][cs], 0, 0, 0);
                o_acc[1][cs] = __builtin_amdgcn_mfma_f32_16x16x32_bf16(pf1, vf, o_acc[1][cs], 0, 0, 0);
            }
        }
        __syncthreads();   // all P/V reads done before next-tile restage
    }

#pragma unroll
    for (int ms = 0; ms < 2; ++ms)
#pragma unroll
        for (int r = 0; r < 4; ++r) {
            l_r[ms][r] += __shfl_xor(l_r[ms][r], 1);
            l_r[ms][r] += __shfl_xor(l_r[ms][r], 2);
            l_r[ms][r] += __shfl_xor(l_r[ms][r], 4);
            l_r[ms][r] += __shfl_xor(l_r[ms][r], 8);
        }

    if (Opb) {
#pragma unroll
        for (int ms = 0; ms < 2; ++ms) {
#pragma unroll
            for (int cs = 0; cs < 8; ++cs)
#pragma unroll
                for (int r = 0; r < 4; ++r) {
                    size_t row = (size_t)s * (B_ * N_) + (size_t)b * N_ +
                                 m0 + wave * 32 + ms * 16 + quad * 4 + r;
                    Opb[row * C2_ + cs * 16 + l16] = f2bf(o_acc[ms][cs][r]);
                }
            if (l16 == 0)
#pragma unroll
                for (int r = 0; r < 4; ++r) {
                    size_t row = (size_t)s * (B_ * N_) + (size_t)b * N_ +
                                 m0 + wave * 32 + ms * 16 + quad * 4 + r;
                    lsum[row] = l_r[ms][r];
                }
        }
    } else {
#pragma unroll
        for (int ms = 0; ms < 2; ++ms)
#pragma unroll
            for (int cs = 0; cs < 8; ++cs)
#pragma unroll
                for (int r = 0; r < 4; ++r) {
                    float v = o_acc[ms][cs][r] / l_r[ms][r];
                    AO[((size_t)b * N_ + m0 + wave * 32 + ms * 16 + quad * 4 + r) * C2_ +
                       cs * 16 + l16] = f2bf(v);
                }
    }
}

// ---------------------------------------------------------------------------
// Kernel 3: outproj with fused split-K combine (nsplit=8).
// LDS: 2*17920 + 256 = 36096 B -> 4 blocks/CU; light register use so the
// (256,4) bound does not spill here.
// ---------------------------------------------------------------------------
#define OW 140

__global__ __launch_bounds__(256, 4) void outproj_kernel(
    const float* __restrict__ x, const u16* __restrict__ Opb,
    const float* __restrict__ lsum, const u16* __restrict__ AO,
    const float* __restrict__ w_out, const float* __restrict__ b_out,
    float* __restrict__ y, int nsplit) {
    __shared__ __align__(16) u16 As[64][OW];     // 17920 B
    __shared__ __align__(16) u16 Ws2[64][OW];    // 17920 B
    __shared__ float Ls[64];
    int bid = blockIdx.x;
    int per_b = (C_ / 64) * (N_ / 64);   // 256
    int b   = bid / per_b;
    int rem = bid % per_b;
    int c0  = (rem / (N_ / 64)) * 64;
    int n0  = (rem % (N_ / 64)) * 64;
    int tid = threadIdx.x;
    int wave = tid >> 6, lane = tid & 63, quad = (lane >> 4) & 3, l16 = lane & 15;

    // ---- stage w_out tile [64 c][128 c2] fp32 -> Ws2 bf16 (coalesced) ----
#pragma unroll
    for (int it = 0; it < 4; ++it) {
        int idx = it * 256 + tid;
        int row = idx >> 4, c8 = (idx & 15) * 8;
        const float* src = w_out + (size_t)(c0 + row) * C2_ + c8;
        float w8[8];
        *(float4*)&w8[0] = *(const float4*)src;
        *(float4*)&w8[4] = *(const float4*)(src + 4);
        st8(&Ws2[row][c8], cvt8(w8));
    }

    if (nsplit > 1) {   // grid-uniform branch
        if (tid < 64) {
            float L = 0.f;
            for (int s = 0; s < nsplit; ++s)
                L += lsum[(size_t)s * (B_ * N_) + (size_t)b * N_ + n0 + tid];
            Ls[tid] = 1.f / L;
        }
        __syncthreads();
#pragma unroll
        for (int it = 0; it < 4; ++it) {
            int idx = it * 256 + tid;
            int n = idx >> 4, c8 = (idx & 15) * 8;
            float a[8] = {0.f, 0.f, 0.f, 0.f, 0.f, 0.f, 0.f, 0.f};
            for (int s = 0; s < nsplit; ++s) {
                const u16* op = Opb +
                    ((size_t)s * (B_ * N_) + (size_t)b * N_ + n0 + n) * C2_ + c8;
                uint4 raw = *(const uint4*)op;
                const u16* rp = (const u16*)&raw;
#pragma unroll
                for (int j = 0; j < 8; ++j) a[j] += bf2f(rp[j]);
            }
            float inv = Ls[n];
            u16 o[8];
#pragma unroll
            for (int j = 0; j < 8; ++j) o[j] = f2bf(a[j] * inv);
            st8(&As[n][c8], *(const bf16x8*)o);
        }
    } else {
#pragma unroll
        for (int it = 0; it < 4; ++it) {
            int idx = it * 256 + tid;
            int n = idx >> 4, c8 = (idx & 15) * 8;
            uint4 raw = *(const uint4*)(AO + ((size_t)b * N_ + n0 + n) * C2_ + c8);
            *(uint2*)&As[n][c8]     = make_uint2(raw.x, raw.y);
            *(uint2*)&As[n][c8 + 4] = make_uint2(raw.z, raw.w);
        }
    }
    __syncthreads();

    bf16x8 af[4];
#pragma unroll
    for (int kk = 0; kk < 4; ++kk)
        af[kk] = lds8(&Ws2[wave * 16 + l16][kk * 32 + quad * 8]);

    f32x4 acc[4];
#pragma unroll
    for (int i = 0; i < 4; ++i) acc[i] = (f32x4){0.f, 0.f, 0.f, 0.f};

#pragma unroll
    for (int nn = 0; nn < 4; ++nn)
#pragma unroll
        for (int kk = 0; kk < 4; ++kk) {
            bf16x8 bf = lds8(&As[nn * 16 + l16][kk * 32 + quad * 8]);
            acc[nn] = __builtin_amdgcn_mfma_f32_16x16x32_bf16(af[kk], bf, acc[nn], 0, 0, 0);
        }

    int cw = c0 + wave * 16;
    float bo[4];
#pragma unroll
    for (int r = 0; r < 4; ++r) bo[r] = b_out[cw + quad * 4 + r];

#pragma unroll
    for (int nn = 0; nn < 4; ++nn)
#pragma unroll
        for (int r = 0; r < 4; ++r) {
            int c = cw + quad * 4 + r;
            size_t off = ((size_t)b * C_ + c) * N_ + n0 + nn * 16 + l16;
            y[off] = x[off] + bo[r] + acc[nn][r];
        }
}

// ---------------------------------------------------------------------------
extern "C" void kernel_launch(void* const* d_in, const int* in_sizes, int n_in,
                              void* d_out, int out_size, void* d_ws, size_t ws_size,
                              hipStream_t stream) {
    const float* x       = (const float*)d_in[0];
    const float* w_theta = (const float*)d_in[1];
    const float* b_theta = (const float*)d_in[2];
    const float* w_phi   = (const float*)d_in[3];
    const float* b_phi   = (const float*)d_in[4];
    const float* w_g     = (const float*)d_in[5];
    const float* b_g     = (const float*)d_in[6];
    const float* w_out   = (const float*)d_in[7];
    const float* b_out   = (const float*)d_in[8];
    float* y = (float*)d_out;

    const size_t SZ = (size_t)B_ * N_ * C2_;        // 2Mi elements
    u16* Q = (u16*)d_ws;
    u16* K = Q + SZ;
    u16* V = K + SZ;
    char* dyn = (char*)(V + SZ);
    size_t fixedB = 3 * SZ * 2;                      // 12 MiB

    size_t perS = SZ * 2 + (size_t)B_ * N_ * 4;      // Opb bf16 + lsum per split

    int S;
    if      (ws_size >= fixedB + 8 * perS) S = 8;    // grid 1024 = 4 blk/CU
    else if (ws_size >= fixedB + 4 * perS) S = 4;
    else if (ws_size >= fixedB + 2 * perS) S = 2;
    else                                   S = 1;

    u16*   AO  = (u16*)dyn;       // used only when S == 1
    u16*   Opb = nullptr;
    float* ls  = nullptr;
    if (S > 1) {
        Opb = (u16*)dyn;          // aliases AO (AO unused when split)
        ls  = (float*)(Opb + (size_t)S * SZ);
    }

    projx_kernel<<<B_ * (N_ / 64) * 2, 256, 0, stream>>>(
        x, w_theta, w_phi, w_g, b_theta, b_phi, b_g, Q, K, V);
    attn_kernel<<<B_ * (N_ / 128) * S, 256, 0, stream>>>(Q, K, V, AO, Opb, ls, S);
    outproj_kernel<<<B_ * (C_ / 64) * (N_ / 64), 256, 0, stream>>>(
        x, Opb, ls, AO, w_out, b_out, y, S);
}